// Round 1
// 1093.966 us; speedup vs baseline: 1.0059x; 1.0059x over previous
//
#include <hip/hip_runtime.h>
#include <hip/hip_bf16.h>

// Problem constants (B=4, L=2048, D=1024, H=4096, E=8, K=2)
#define NTOK   8192
#define DDIM   1024
#define HDIM   4096
#define NEXP   8
#define CAP    8192
#define NSLOT  (NTOK * 2)

// GEMM tiling (m97 structure: unpadded LDS, global_load_lds width-16 staging)
#define BM 128
#define BN 128
#define BK 64

typedef __attribute__((ext_vector_type(8))) short bf16x8;
typedef __attribute__((ext_vector_type(4))) float f32x4;

// async global->LDS, 16B per lane; LDS dest = wave-uniform base + lane*16
#define GLD16(g, l) __builtin_amdgcn_global_load_lds(                          \
    (const __attribute__((address_space(1))) void*)(g),                        \
    (__attribute__((address_space(3))) void*)(l), 16, 0, 0)

// ---------------- Router: logits -> top2 -> softmax -> expert lists ----------------
__global__ __launch_bounds__(64) void router_kernel(
    const float* __restrict__ xs, const float* __restrict__ gw,
    int* __restrict__ counts, int* __restrict__ toklist, float* __restrict__ wglist)
{
    const int n = blockIdx.x;
    const int lane = threadIdx.x;
    const float* xrow = xs + (size_t)n * DDIM;
    float xv[16];
#pragma unroll
    for (int j = 0; j < 16; ++j) xv[j] = xrow[lane + 64 * j];
    float logit[NEXP];
#pragma unroll
    for (int e = 0; e < NEXP; ++e) {
        float p = 0.f;
        const float* gr = gw + e * DDIM;
#pragma unroll
        for (int j = 0; j < 16; ++j) p += xv[j] * gr[lane + 64 * j];
#pragma unroll
        for (int off = 32; off >= 1; off >>= 1) p += __shfl_xor(p, off);
        logit[e] = p;
    }
    if (lane == 0) {
        int i0 = 0;
#pragma unroll
        for (int e = 1; e < NEXP; ++e) if (logit[e] > logit[i0]) i0 = e;
        int i1 = (i0 == 0) ? 1 : 0;
#pragma unroll
        for (int e = 0; e < NEXP; ++e) if (e != i0 && logit[e] > logit[i1]) i1 = e;
        float ex = expf(logit[i1] - logit[i0]);
        float w0 = 1.f / (1.f + ex);
        float w1 = ex * w0;
        int p0 = atomicAdd(&counts[i0], 1);
        toklist[i0 * CAP + p0] = n;
        wglist[i0 * CAP + p0] = w0;
        int p1 = atomicAdd(&counts[i1], 1);
        toklist[i1 * CAP + p1] = n;
        wglist[i1 * CAP + p1] = w1;
    }
}

__global__ void prefix_kernel(const int* __restrict__ counts, int* __restrict__ base)
{
    if (threadIdx.x == 0 && blockIdx.x == 0) {
        int s = 0;
        for (int e = 0; e < NEXP; ++e) { base[e] = s; s += counts[e]; }
    }
}

// ---------------- xs fp32 -> bf16 ----------------
__global__ __launch_bounds__(256) void cvt_xs_kernel(
    const float* __restrict__ xs, __hip_bfloat16* __restrict__ xsb)
{
    const size_t i = ((size_t)blockIdx.x * 256 + threadIdx.x) * 8;
    const float4 a = *(const float4*)(xs + i);
    const float4 b = *(const float4*)(xs + i + 4);
    __hip_bfloat16 o[8];
    o[0] = __float2bfloat16(a.x); o[1] = __float2bfloat16(a.y);
    o[2] = __float2bfloat16(a.z); o[3] = __float2bfloat16(a.w);
    o[4] = __float2bfloat16(b.x); o[5] = __float2bfloat16(b.y);
    o[6] = __float2bfloat16(b.z); o[7] = __float2bfloat16(b.w);
    *(bf16x8*)(xsb + i) = *(bf16x8*)o;
}

// ---------------- per-expert transpose fp32 (RxC) -> bf16 (CxR) ----------------
__global__ __launch_bounds__(256) void transpose_bf16_kernel(
    const float* __restrict__ src, __hip_bfloat16* __restrict__ dst, int R, int C)
{
    __shared__ __hip_bfloat16 t[64][72];
    const int e = blockIdx.z;
    src += (size_t)e * R * C;
    dst += (size_t)e * R * C;
    const int r0 = blockIdx.y * 64, c0 = blockIdx.x * 64;
    const int tid = threadIdx.x;
#pragma unroll
    for (int i = 0; i < 4; ++i) {
        int r = (tid >> 4) + 16 * i;
        int c = (tid & 15) * 4;
        float4 v = *(const float4*)(src + (size_t)(r0 + r) * C + c0 + c);
        t[r][c + 0] = __float2bfloat16(v.x);
        t[r][c + 1] = __float2bfloat16(v.y);
        t[r][c + 2] = __float2bfloat16(v.z);
        t[r][c + 3] = __float2bfloat16(v.w);
    }
    __syncthreads();
#pragma unroll
    for (int i = 0; i < 4; ++i) {
        int c = (tid >> 4) + 16 * i;
        int r = (tid & 15) * 4;
        __hip_bfloat16 o[4] = { t[r][c], t[r + 1][c], t[r + 2][c], t[r + 3][c] };
        *(short4*)(dst + (size_t)(c0 + c) * R + r0 + r) = *(short4*)o;
    }
}

// ---------------- GEMM1: h[slot][:] = relu(x[tok] @ w1[e]), bf16 out ----------------
// 1-D grid (16384 blocks). XCD-bijective remap, expert-major chunking:
// XCD k owns expert k's full (my, nx) slice; nx fastest for A-panel L2 reuse.
__global__ __launch_bounds__(256) void gemm1_kernel(
    const __hip_bfloat16* __restrict__ xsb, const __hip_bfloat16* __restrict__ w1t,
    const int* __restrict__ counts, const int* __restrict__ base,
    const int* __restrict__ toklist, __hip_bfloat16* __restrict__ h)
{
    const unsigned bidx = blockIdx.x;
    const unsigned w = (bidx & 7u) * 2048u + (bidx >> 3);   // bijective: 16384 % 8 == 0
    const int e  = w >> 11;             // 0..7  (expert == XCD)
    const int m0 = ((w >> 5) & 63) * BM;
    const int n0 = (w & 31) * BN;

    const int cnt = counts[e];
    if (m0 >= cnt) return;

    __shared__ __align__(16) __hip_bfloat16 As[BM * BK];
    __shared__ __align__(16) __hip_bfloat16 Bs[BN * BK];
    __shared__ int tok_s[BM];

    const int tid = threadIdx.x;
    if (tid < BM) tok_s[tid] = toklist[e * CAP + min(m0 + tid, cnt - 1)];
    __syncthreads();

    const int wave = tid >> 6;
    const int lane = tid & 63;
    const int lrow = lane >> 3;          // 0..7
    const int lcol = (lane & 7) * 8;     // k elems
    const __hip_bfloat16* w1e = w1t + (size_t)e * HDIM * DDIM;

    const __hip_bfloat16* srcA[4];
    const __hip_bfloat16* srcB[4];
#pragma unroll
    for (int c = 0; c < 4; ++c) {
        int r = wave * 32 + c * 8 + lrow;
        srcA[c] = xsb + (size_t)tok_s[r] * DDIM + lcol;
        srcB[c] = w1e + (size_t)(n0 + r) * DDIM + lcol;
    }

    f32x4 acc[4][4];
#pragma unroll
    for (int i = 0; i < 4; ++i)
#pragma unroll
        for (int j = 0; j < 4; ++j) acc[i][j] = (f32x4){0.f, 0.f, 0.f, 0.f};

    const int wm = (wave >> 1) * 64;
    const int wn = (wave & 1) * 64;
    const int l15 = lane & 15;
    const int quad = lane >> 4;

    for (int k0 = 0; k0 < DDIM; k0 += BK) {
#pragma unroll
        for (int c = 0; c < 4; ++c) {
            GLD16(srcA[c] + k0, As + (wave * 32 + c * 8) * BK);
            GLD16(srcB[c] + k0, Bs + (wave * 32 + c * 8) * BK);
        }
        __syncthreads();
#pragma unroll
        for (int kk = 0; kk < 2; ++kk) {
            bf16x8 a[4], b[4];
#pragma unroll
            for (int i = 0; i < 4; ++i)
                a[i] = *(const bf16x8*)(As + (wm + i * 16 + l15) * BK + kk * 32 + quad * 8);
#pragma unroll
            for (int j = 0; j < 4; ++j)
                b[j] = *(const bf16x8*)(Bs + (wn + j * 16 + l15) * BK + kk * 32 + quad * 8);
#pragma unroll
            for (int i = 0; i < 4; ++i)
#pragma unroll
                for (int j = 0; j < 4; ++j)
                    acc[i][j] = __builtin_amdgcn_mfma_f32_16x16x32_bf16(a[i], b[j], acc[i][j], 0, 0, 0);
        }
        __syncthreads();
    }

    const int slot0 = base[e] + m0;
#pragma unroll
    for (int i = 0; i < 4; ++i) {
#pragma unroll
        for (int r = 0; r < 4; ++r) {
            int row = wm + i * 16 + quad * 4 + r;
            if (m0 + row < cnt) {
                size_t hrow = (size_t)(slot0 + row) * HDIM + n0 + wn;
#pragma unroll
                for (int j = 0; j < 4; ++j)
                    h[hrow + j * 16 + l15] = __float2bfloat16(fmaxf(acc[i][j][r], 0.f));
            }
        }
    }
}

// ---------------- GEMM2: out[tok][:] += w * (h[slot] @ w2[e]) ----------------
// 1-D grid (4096 blocks). Same XCD-bijective expert-major remap (chunk = 512).
__global__ __launch_bounds__(256) void gemm2_kernel(
    const __hip_bfloat16* __restrict__ h, const __hip_bfloat16* __restrict__ w2t,
    const int* __restrict__ counts, const int* __restrict__ base,
    const int* __restrict__ toklist, const float* __restrict__ wglist,
    float* __restrict__ out)
{
    const unsigned bidx = blockIdx.x;
    const unsigned w = (bidx & 7u) * 512u + (bidx >> 3);    // bijective: 4096 % 8 == 0
    const int e  = w >> 9;              // 0..7  (expert == XCD)
    const int m0 = ((w >> 3) & 63) * BM;
    const int n0 = (w & 7) * BN;

    const int cnt = counts[e];
    if (m0 >= cnt) return;

    __shared__ __align__(16) __hip_bfloat16 As[BM * BK];
    __shared__ __align__(16) __hip_bfloat16 Bs[BN * BK];
    __shared__ int   tok_s[BM];
    __shared__ float wg_s[BM];

    const int tid = threadIdx.x;
    if (tid < BM) {
        int m = m0 + tid;
        tok_s[tid] = (m < cnt) ? toklist[e * CAP + m] : -1;
        wg_s[tid]  = (m < cnt) ? wglist[e * CAP + m] : 0.f;
    }
    __syncthreads();

    const int wave = tid >> 6;
    const int lane = tid & 63;
    const int lrow = lane >> 3;
    const int lcol = (lane & 7) * 8;
    const int slot0 = base[e];
    const __hip_bfloat16* w2e = w2t + (size_t)e * DDIM * HDIM;

    const __hip_bfloat16* srcA[4];
    const __hip_bfloat16* srcB[4];
#pragma unroll
    for (int c = 0; c < 4; ++c) {
        int r = wave * 32 + c * 8 + lrow;
        srcA[c] = h + (size_t)(slot0 + min(m0 + r, cnt - 1)) * HDIM + lcol;
        srcB[c] = w2e + (size_t)(n0 + r) * HDIM + lcol;
    }

    f32x4 acc[4][4];
#pragma unroll
    for (int i = 0; i < 4; ++i)
#pragma unroll
        for (int j = 0; j < 4; ++j) acc[i][j] = (f32x4){0.f, 0.f, 0.f, 0.f};

    const int wm = (wave >> 1) * 64;
    const int wn = (wave & 1) * 64;
    const int l15 = lane & 15;
    const int quad = lane >> 4;

    for (int k0 = 0; k0 < HDIM; k0 += BK) {
#pragma unroll
        for (int c = 0; c < 4; ++c) {
            GLD16(srcA[c] + k0, As + (wave * 32 + c * 8) * BK);
            GLD16(srcB[c] + k0, Bs + (wave * 32 + c * 8) * BK);
        }
        __syncthreads();
#pragma unroll
        for (int kk = 0; kk < 2; ++kk) {
            bf16x8 a[4], b[4];
#pragma unroll
            for (int i = 0; i < 4; ++i)
                a[i] = *(const bf16x8*)(As + (wm + i * 16 + l15) * BK + kk * 32 + quad * 8);
#pragma unroll
            for (int j = 0; j < 4; ++j)
                b[j] = *(const bf16x8*)(Bs + (wn + j * 16 + l15) * BK + kk * 32 + quad * 8);
#pragma unroll
            for (int i = 0; i < 4; ++i)
#pragma unroll
                for (int j = 0; j < 4; ++j)
                    acc[i][j] = __builtin_amdgcn_mfma_f32_16x16x32_bf16(a[i], b[j], acc[i][j], 0, 0, 0);
        }
        __syncthreads();
    }

#pragma unroll
    for (int i = 0; i < 4; ++i) {
#pragma unroll
        for (int r = 0; r < 4; ++r) {
            int row = wm + i * 16 + quad * 4 + r;
            if (m0 + row < cnt) {
                int tok = tok_s[row];
                float wgt = wg_s[row];
                float* orow = out + (size_t)tok * DDIM + n0 + wn;
#pragma unroll
                for (int j = 0; j < 4; ++j)
                    atomicAdd(&orow[j * 16 + l15], wgt * acc[i][j][r]);
            }
        }
    }
}

extern "C" void kernel_launch(void* const* d_in, const int* in_sizes, int n_in,
                              void* d_out, int out_size, void* d_ws, size_t ws_size,
                              hipStream_t stream)
{
    const float* xs = (const float*)d_in[0];   // (B,L,D) fp32
    const float* gw = (const float*)d_in[1];   // (E,D)
    const float* w1 = (const float*)d_in[2];   // (E,D,H)
    const float* w2 = (const float*)d_in[3];   // (E,H,D)
    float* out = (float*)d_out;

    char* ws = (char*)d_ws;
    size_t o = 0;
    int*   counts  = (int*)(ws + o);  o += 256;
    int*   base    = (int*)(ws + o);  o += 256;
    int*   toklist = (int*)(ws + o);  o += (size_t)NEXP * CAP * 4;
    float* wglist  = (float*)(ws + o); o += (size_t)NEXP * CAP * 4;
    __hip_bfloat16* xsb = (__hip_bfloat16*)(ws + o); o += (size_t)NTOK * DDIM * 2;
    __hip_bfloat16* w1t = (__hip_bfloat16*)(ws + o); o += (size_t)NEXP * DDIM * HDIM * 2;
    __hip_bfloat16* w2t = (__hip_bfloat16*)(ws + o); o += (size_t)NEXP * DDIM * HDIM * 2;
    __hip_bfloat16* hbuf = (__hip_bfloat16*)(ws + o); o += (size_t)NSLOT * HDIM * 2;

    hipMemsetAsync(counts, 0, 256, stream);
    hipMemsetAsync(d_out, 0, (size_t)out_size * sizeof(float), stream);

    router_kernel<<<NTOK, 64, 0, stream>>>(xs, gw, counts, toklist, wglist);
    prefix_kernel<<<1, 64, 0, stream>>>(counts, base);
    cvt_xs_kernel<<<(NTOK * DDIM) / (256 * 8), 256, 0, stream>>>(xs, xsb);
    transpose_bf16_kernel<<<dim3(HDIM / 64, DDIM / 64, NEXP), 256, 0, stream>>>(w1, w1t, DDIM, HDIM);
    transpose_bf16_kernel<<<dim3(DDIM / 64, HDIM / 64, NEXP), 256, 0, stream>>>(w2, w2t, HDIM, DDIM);

    gemm1_kernel<<<32 * 64 * NEXP, 256, 0, stream>>>(
        xsb, w1t, counts, base, toklist, hbuf);
    gemm2_kernel<<<8 * 64 * NEXP, 256, 0, stream>>>(
        hbuf, w2t, counts, base, toklist, wglist, out);
}